// Round 8
// baseline (2864.625 us; speedup 1.0000x reference)
//
#include <hip/hip_runtime.h>
#include <hip/hip_bf16.h>
#include <stdint.h>

#define Bb 32
#define Lx 512
#define Cc 256
#define Tt 4
#define HID 1024
#define RR (Bb*Lx)          // 16384 logical rows (b*L+l)
#define CH 8192             // rows r per chunk
#define MR (CH*Tt)          // 32768 interleaved rows (r*4+t) per chunk
#define NCHUNK (RR/CH)      // 2

typedef int i32x4 __attribute__((ext_vector_type(4)));

// ---------------- async global->LDS, 16B per lane
__device__ __forceinline__ void gl16(const void* g, void* l) {
    __builtin_amdgcn_global_load_lds(
        (const __attribute__((address_space(1))) unsigned int*)g,
        (__attribute__((address_space(3))) unsigned int*)l, 16, 0, 0);
}
__device__ __forceinline__ void blockbar() {
    asm volatile("" ::: "memory");
    __builtin_amdgcn_s_barrier();
    asm volatile("" ::: "memory");
}

// stage one 256row x 64B operand tile into LDS (4 sweeps of 64 rows), linear dest,
// source slot pre-swizzled with involution slot^((row>>1)&3) (rule #21).
// 256 threads x 4 gl16 x 16B = 16 KB.
__device__ __forceinline__ void stage_op(const int8_t* __restrict__ g, int K_,
                                         int baseRow, int ko, int8_t* ldsb,
                                         int srow, int sl, int tid) {
    #pragma unroll
    for (int s = 0; s < 4; ++s)
        gl16(g + (size_t)(baseRow + s*64 + srow) * K_ + ko + sl*16,
             ldsb + s*4096 + tid*16);
}

// ---------------- weight quantization: w*2^s = i1*2^14 + i2*2^7 + i3 (exact fixed point)
__global__ void zero_f(float* p, int n) {
    if ((int)threadIdx.x < n) p[threadIdx.x] = 0.0f;
}
__global__ void absmax_k(const float* __restrict__ w, int n, float* __restrict__ out) {
    float v = 0.0f;
    for (int i = blockIdx.x*256 + threadIdx.x; i < n; i += gridDim.x*256)
        v = fmaxf(v, fabsf(w[i]));
    #pragma unroll
    for (int o = 32; o; o >>= 1) v = fmaxf(v, __shfl_down(v, o));
    if ((threadIdx.x & 63) == 0)
        atomicMax((unsigned*)out, __float_as_uint(v));   // positives: bit-max == val-max
}
__global__ void quant_k(const float* __restrict__ w, int n,
                        const float* __restrict__ amax,
                        int8_t* __restrict__ q, float* __restrict__ invOut) {
    float m = fmaxf(amax[0], 1e-20f);
    float e = floorf(log2f(126.0f * 16384.0f / m));
    float sp = exp2f(e);
    if (m * sp > 126.0f * 16384.0f) sp *= 0.5f;     // guard log2 boundary
    if (blockIdx.x == 0 && threadIdx.x == 0) invOut[0] = 1.0f / sp;
    int i = blockIdx.x*256 + threadIdx.x;
    if (i >= n) return;
    float v  = rintf(w[i] * sp);                    // |v| <= 126*2^14, integer-exact in f32
    float i1 = rintf(v * (1.0f/16384.0f));          // |i1| <= 126
    float r1 = v - i1 * 16384.0f;                   // |r1| <= 2^13, exact
    float i2 = rintf(r1 * (1.0f/128.0f));           // |i2| <= 64
    float r2 = r1 - i2 * 128.0f;                    // |r2| <= 64, exact
    q[i]               = (int8_t)i1;
    q[(size_t)n + i]   = (int8_t)i2;
    q[(size_t)2*n + i] = (int8_t)r2;
}

// ---------------- Stage 1: conv(K=3 over L) + BN + LIF -> i8 spikes, rows r*4+t
__global__ void conv_bn_lif(const float* __restrict__ x,
                            const float* __restrict__ cw, const float* __restrict__ cb,
                            const float* __restrict__ g,  const float* __restrict__ be,
                            const float* __restrict__ mu, const float* __restrict__ var,
                            int8_t* __restrict__ spk) {   // [RR*4][Cc]
    int idx = blockIdx.x * blockDim.x + threadIdx.x;
    if (idx >= Bb*Lx*Cc) return;
    int bl = idx / Cc;
    int c  = idx % Cc;
    int l  = bl % Lx;
    float x0 = x[idx];
    float xm = (l > 0)    ? x[idx - Cc] : 0.0f;
    float xp = (l < Lx-1) ? x[idx + Cc] : 0.0f;
    float v = 0.0f;
    #pragma unroll
    for (int t = 0; t < Tt; ++t) {
        float y = cw[t*3+0]*xm + cw[t*3+1]*x0 + cw[t*3+2]*xp + cb[t];
        float inv = g[t] / sqrtf(var[t] + 1e-5f);
        y = (y - mu[t]) * inv + be[t];
        v = v + (y - v) * 0.5f;
        float s = (v >= 1.0f) ? 1.0f : 0.0f;
        spk[(size_t)(bl*4 + t)*Cc + c] = (int8_t)s;
        v = v * (1.0f - s);
    }
}

// ---------------- i8 3-pass GEMM + LIF epilogue
// Tile 256x256, BK=64, 4 waves (2x2), wave tile 128x128, acc[8][8].
// 2 LDS buffers of 32 KB -> 64 KB total -> 2 blocks/CU (16 waves/CU): cross-block
// phase diversity breaks the read/MFMA convoy. Single barrier + vmcnt(0) per tile.
// acc = (acc1*128 + acc2)*128 + acc3 exact in i32 (|acc| < 2^31).
template<int K, bool FINAL>
__global__ __launch_bounds__(256, 2)
void gemm_lif(const int8_t* __restrict__ A,
              const int8_t* __restrict__ Wq,      // [3 comps][HID][K]
              const float* __restrict__ invs,     // [1] 2^-s
              const float* __restrict__ bias,
              int8_t* __restrict__ spk_out, float* __restrict__ out_mean) {
    constexpr int KT  = K / 64;           // tiles per component pass
    constexpr int NKT = 3 * KT;           // three fixed-point component passes
    __shared__ int8_t lds[2 * 32768];     // 2 bufs x (A 16KB + B 16KB)

    const int tid  = threadIdx.x;
    const int lane = tid & 63;
    const int wid  = tid >> 6;
    const int wm   = wid >> 1;        // 0..1
    const int wn   = wid & 1;         // 0..1
    // XCD-chunked decode: XCD k covers m-panels {k, k+8, ...} x all 4 n-panels
    const int bid  = blockIdx.x;
    const int m0   = (((bid >> 5) << 3) + (bid & 7)) * 256;
    const int n0   = ((bid >> 3) & 3) * 256;
    const int fr   = lane & 15;
    const int lq   = lane >> 4;
    const int swq  = (lq ^ ((fr >> 1) & 3)) * 16;   // conflict-free phys byte slot in 64B row
    const int srow = tid >> 2;                      // staging row within sweep
    const int sl   = (tid & 3) ^ ((srow >> 1) & 3); // pre-swizzled source slot

    i32x4 acc[8][8] = {};

    // ---- prologue: stage tile 0 (component 0, ko=0) into buf0
    stage_op(A,  K, m0, 0, &lds[0],     srow, sl, tid);
    stage_op(Wq, K, n0, 0, &lds[16384], srow, sl, tid);

    #pragma unroll 1
    for (int kt = 0; kt < NKT; ++kt) {
        if (kt == KT || kt == 2*KT) {     // component boundary: shift accumulated value
            #pragma unroll
            for (int i = 0; i < 8; ++i)
                #pragma unroll
                for (int j = 0; j < 8; ++j)
                    acc[i][j] *= 128;
        }
        asm volatile("s_waitcnt vmcnt(0)" ::: "memory");   // tile kt landed (issued 1 tile ago)
        blockbar();

        const int cb = (kt & 1) * 32768;
        // ---- issue sweeps for tile kt+1 into the other buffer
        if (kt + 1 < NKT) {
            const int t1 = kt + 1;
            const int pb = (t1 & 1) * 32768;
            const int ko = (t1 % KT) * 64;
            const int8_t* Wc = Wq + (size_t)(t1 / KT) * HID * K;
            stage_op(A,  K, m0, ko, &lds[pb],         srow, sl, tid);
            stage_op(Wc, K, n0, ko, &lds[pb + 16384], srow, sl, tid);
        }

        // ---- 16 ds_read_b128 + 64 MFMA; compiler inserts counted lgkm waits
        i32x4 af[8], bf[8];
        #pragma unroll
        for (int i = 0; i < 8; ++i)
            af[i] = *(const i32x4*)&lds[cb + (wm*128 + i*16 + fr)*64 + swq];
        #pragma unroll
        for (int j = 0; j < 8; ++j)
            bf[j] = *(const i32x4*)&lds[cb + 16384 + (wn*128 + j*16 + fr)*64 + swq];
        __builtin_amdgcn_s_setprio(1);
        #pragma unroll
        for (int i = 0; i < 8; ++i)
            #pragma unroll
            for (int j = 0; j < 8; ++j)
                acc[i][j] = __builtin_amdgcn_mfma_i32_16x16x64_i8(af[i], bf[j], acc[i][j], 0, 0, 0);
        __builtin_amdgcn_s_setprio(0);
    }

    // ---- epilogue: per-lane LIF over 4 acc regs (= 4 timesteps of one row)
    const float inv = invs[0];
    float bs[8];
    #pragma unroll
    for (int j = 0; j < 8; ++j)
        bs[j] = bias[n0 + wn*128 + j*16 + fr];
    const int rowq = lq * 4;
    #pragma unroll
    for (int i = 0; i < 8; ++i) {
        int rowLocal = m0 + wm*128 + i*16 + rowq;   // t=0 row; rows rowLocal..+3 = t 0..3
        int r = rowLocal >> 2;
        #pragma unroll
        for (int j = 0; j < 8; ++j) {
            int n = n0 + wn*128 + j*16 + fr;
            float v = 0.0f, ssum = 0.0f;
            #pragma unroll
            for (int t = 0; t < 4; ++t) {
                float xv = (float)acc[i][j][t] * inv + bs[j];
                v = v + (xv - v) * 0.5f;
                float s = (v >= 1.0f) ? 1.0f : 0.0f;
                if constexpr (FINAL) ssum += s;
                else spk_out[(size_t)(rowLocal + t) * HID + n] = (int8_t)s;
                v = v * (1.0f - s);
            }
            if constexpr (FINAL) out_mean[(size_t)r * HID + n] = ssum * 0.25f;
        }
    }
}

// ---------------- out2[b,d] = mean over L of out1[b,l,d]
__global__ void mean_over_L(const float* __restrict__ out1, float* __restrict__ out2) {
    int idx = blockIdx.x * blockDim.x + threadIdx.x; // B*HID
    if (idx >= Bb*HID) return;
    int b = idx / HID, d = idx % HID;
    const float* p = out1 + (size_t)b*Lx*HID + d;
    float s = 0.0f;
    for (int l = 0; l < Lx; ++l) s += p[(size_t)l*HID];
    out2[idx] = s * (1.0f / Lx);
}

extern "C" void kernel_launch(void* const* d_in, const int* in_sizes, int n_in,
                              void* d_out, int out_size, void* d_ws, size_t ws_size,
                              hipStream_t stream) {
    const float* x      = (const float*)d_in[0];
    const float* cw     = (const float*)d_in[1];
    const float* cb     = (const float*)d_in[2];
    const float* g      = (const float*)d_in[3];
    const float* be     = (const float*)d_in[4];
    const float* mu     = (const float*)d_in[5];
    const float* var    = (const float*)d_in[6];
    const float* enc_w  = (const float*)d_in[7];
    const float* enc_b  = (const float*)d_in[8];
    const float* cell_w = (const float*)d_in[9];
    const float* cell_b = (const float*)d_in[10];

    float* out1 = (float*)d_out;                    // [RR][HID]
    float* out2 = out1 + (size_t)RR * HID;          // [B][HID]

    // ---- ws layout (~87 MB total)
    int8_t* spk1 = (int8_t*)d_ws;                   // RR*4*Cc = 16 MB
    int8_t* spkA = spk1 + (size_t)RR*4*Cc;          // MR*HID  = 32 MB
    int8_t* spkB = spkA + (size_t)MR*HID;           // MR*HID  = 32 MB
    int8_t* qEnc = spkB + (size_t)MR*HID;           // 3*HID*Cc
    int8_t* qC0  = qEnc + (size_t)3*HID*Cc;         // 3*HID*HID
    int8_t* qC1  = qC0  + (size_t)3*HID*HID;        // 3*HID*HID
    float*  amax = (float*)(qC1 + (size_t)3*HID*HID);
    float*  invv = amax + 3;

    // ---- weight quantization (exact 21-bit fixed point, per-matrix pow2 scale)
    zero_f<<<1, 4, 0, stream>>>(amax, 3);
    absmax_k<<<512, 256, 0, stream>>>(enc_w,  HID*Cc,  amax + 0);
    absmax_k<<<512, 256, 0, stream>>>(cell_w, HID*HID, amax + 1);
    absmax_k<<<512, 256, 0, stream>>>(cell_w + (size_t)HID*HID, HID*HID, amax + 2);
    quant_k<<<(HID*Cc  + 255)/256, 256, 0, stream>>>(enc_w,  HID*Cc,  amax + 0, qEnc, invv + 0);
    quant_k<<<(HID*HID + 255)/256, 256, 0, stream>>>(cell_w, HID*HID, amax + 1, qC0,  invv + 1);
    quant_k<<<(HID*HID + 255)/256, 256, 0, stream>>>(cell_w + (size_t)HID*HID, HID*HID, amax + 2, qC1, invv + 2);

    // ---- conv + BN + LIF
    conv_bn_lif<<<(Bb*Lx*Cc + 255)/256, 256, 0, stream>>>(x, cw, cb, g, be, mu, var, spk1);

    // ---- chunked trunk (2 chunks of 8192 rows); 512 blocks = 2/CU
    for (int c = 0; c < NCHUNK; ++c) {
        const int8_t* a1 = spk1 + (size_t)c * MR * Cc;
        gemm_lif<Cc,  false><<<512, 256, 0, stream>>>(a1,   qEnc, invv + 0, enc_b,      spkA, nullptr);
        gemm_lif<HID, false><<<512, 256, 0, stream>>>(spkA, qC0,  invv + 1, cell_b,     spkB, nullptr);
        gemm_lif<HID, true ><<<512, 256, 0, stream>>>(spkB, qC1,  invv + 2, cell_b+HID, nullptr,
                                                      out1 + (size_t)c * CH * HID);
    }

    mean_over_L<<<(Bb*HID + 255)/256, 256, 0, stream>>>(out1, out2);
}

// Round 9
// 532.740 us; speedup vs baseline: 5.3772x; 5.3772x over previous
//
#include <hip/hip_runtime.h>
#include <hip/hip_bf16.h>
#include <stdint.h>

#define Bb 32
#define Lx 512
#define Cc 256
#define Tt 4
#define HID 1024
#define RR (Bb*Lx)          // 16384 logical rows (b*L+l)
#define CH 8192             // rows r per chunk
#define MR (CH*Tt)          // 32768 interleaved rows (r*4+t) per chunk
#define NCHUNK (RR/CH)      // 2

typedef int i32x4 __attribute__((ext_vector_type(4)));

// ---------------- async global->LDS, 16B per lane
__device__ __forceinline__ void gl16(const void* g, void* l) {
    __builtin_amdgcn_global_load_lds(
        (const __attribute__((address_space(1))) unsigned int*)g,
        (__attribute__((address_space(3))) unsigned int*)l, 16, 0, 0);
}
__device__ __forceinline__ void blockbar() {
    asm volatile("" ::: "memory");
    __builtin_amdgcn_s_barrier();
    asm volatile("" ::: "memory");
}

// stage NSx64 rows x 64B of an operand tile into LDS (256 threads: 4KB/sweep),
// linear dest; source slot pre-swizzled with involution slot^((row>>1)&3) (rule #21).
template<int NS>
__device__ __forceinline__ void stage_op(const int8_t* __restrict__ g, int K_,
                                         int baseRow, int ko, int8_t* ldsb,
                                         int srow, int sl, int tid) {
    #pragma unroll
    for (int s = 0; s < NS; ++s)
        gl16(g + (size_t)(baseRow + s*64 + srow) * K_ + ko + sl*16,
             ldsb + s*4096 + tid*16);
}

// ---------------- weight quantization: w*2^s = i1*2^14 + i2*2^7 + i3 (exact fixed point)
__global__ void zero_f(float* p, int n) {
    if ((int)threadIdx.x < n) p[threadIdx.x] = 0.0f;
}
__global__ void absmax_k(const float* __restrict__ w, int n, float* __restrict__ out) {
    float v = 0.0f;
    for (int i = blockIdx.x*256 + threadIdx.x; i < n; i += gridDim.x*256)
        v = fmaxf(v, fabsf(w[i]));
    #pragma unroll
    for (int o = 32; o; o >>= 1) v = fmaxf(v, __shfl_down(v, o));
    if ((threadIdx.x & 63) == 0)
        atomicMax((unsigned*)out, __float_as_uint(v));   // positives: bit-max == val-max
}
__global__ void quant_k(const float* __restrict__ w, int n,
                        const float* __restrict__ amax,
                        int8_t* __restrict__ q, float* __restrict__ invOut) {
    float m = fmaxf(amax[0], 1e-20f);
    float e = floorf(log2f(126.0f * 16384.0f / m));
    float sp = exp2f(e);
    if (m * sp > 126.0f * 16384.0f) sp *= 0.5f;     // guard log2 boundary
    if (blockIdx.x == 0 && threadIdx.x == 0) invOut[0] = 1.0f / sp;
    int i = blockIdx.x*256 + threadIdx.x;
    if (i >= n) return;
    float v  = rintf(w[i] * sp);                    // |v| <= 126*2^14, integer-exact in f32
    float i1 = rintf(v * (1.0f/16384.0f));          // |i1| <= 126
    float r1 = v - i1 * 16384.0f;                   // |r1| <= 2^13, exact
    float i2 = rintf(r1 * (1.0f/128.0f));           // |i2| <= 64
    float r2 = r1 - i2 * 128.0f;                    // |r2| <= 64, exact
    q[i]               = (int8_t)i1;
    q[(size_t)n + i]   = (int8_t)i2;
    q[(size_t)2*n + i] = (int8_t)r2;
}

// ---------------- Stage 1: conv(K=3 over L) + BN + LIF -> i8 spikes, rows r*4+t
__global__ void conv_bn_lif(const float* __restrict__ x,
                            const float* __restrict__ cw, const float* __restrict__ cb,
                            const float* __restrict__ g,  const float* __restrict__ be,
                            const float* __restrict__ mu, const float* __restrict__ var,
                            int8_t* __restrict__ spk) {   // [RR*4][Cc]
    int idx = blockIdx.x * blockDim.x + threadIdx.x;
    if (idx >= Bb*Lx*Cc) return;
    int bl = idx / Cc;
    int c  = idx % Cc;
    int l  = bl % Lx;
    float x0 = x[idx];
    float xm = (l > 0)    ? x[idx - Cc] : 0.0f;
    float xp = (l < Lx-1) ? x[idx + Cc] : 0.0f;
    float v = 0.0f;
    #pragma unroll
    for (int t = 0; t < Tt; ++t) {
        float y = cw[t*3+0]*xm + cw[t*3+1]*x0 + cw[t*3+2]*xp + cb[t];
        float inv = g[t] / sqrtf(var[t] + 1e-5f);
        y = (y - mu[t]) * inv + be[t];
        v = v + (y - v) * 0.5f;
        float s = (v >= 1.0f) ? 1.0f : 0.0f;
        spk[(size_t)(bl*4 + t)*Cc + c] = (int8_t)s;
        v = v * (1.0f - s);
    }
}

// ---------------- i8 3-pass GEMM + LIF epilogue
// Block tile 256x128, BK=64, 4 waves (2x2), wave tile 128x64 (acc[8][4]=128 AGPR,
// proven no-spill). 2 LDS bufs x (A 16KB + B 8KB) = 48KB -> 2 blocks/CU: two
// independent barrier domains decorrelate LDS-read and MFMA phases.
// acc = (acc1*128 + acc2)*128 + acc3 exact in i32 (|acc| < 2^31).
template<int K, bool FINAL>
__global__ __launch_bounds__(256, 2)
void gemm_lif(const int8_t* __restrict__ A,
              const int8_t* __restrict__ Wq,      // [3 comps][HID][K]
              const float* __restrict__ invs,     // [1] 2^-s
              const float* __restrict__ bias,
              int8_t* __restrict__ spk_out, float* __restrict__ out_mean) {
    constexpr int KT  = K / 64;           // tiles per component pass
    constexpr int NKT = 3 * KT;           // three fixed-point component passes
    __shared__ int8_t lds[2 * 24576];     // 2 bufs x (A 16KB + B 8KB)

    const int tid  = threadIdx.x;
    const int lane = tid & 63;
    const int wid  = tid >> 6;
    const int wm   = wid >> 1;        // 0..1
    const int wn   = wid & 1;         // 0..1
    // XCD-chunked decode (1024 blocks): xcd = bid&7 owns m-panels [xcd*16, xcd*16+16);
    // within an XCD, n sweeps fast (8 n-panels share one L2-resident A panel).
    const int bid  = blockIdx.x;
    const int idx_ = bid >> 3;
    const int m0   = ((bid & 7) * 16 + (idx_ >> 3)) * 256;
    const int n0   = (idx_ & 7) * 128;
    const int fr   = lane & 15;
    const int lq   = lane >> 4;
    const int swq  = (lq ^ ((fr >> 1) & 3)) * 16;   // conflict-free phys byte slot in 64B row
    const int srow = tid >> 2;                      // staging row within sweep (0..63)
    const int sl   = (tid & 3) ^ ((srow >> 1) & 3); // pre-swizzled source slot

    i32x4 acc[8][4] = {};

    // ---- prologue: stage tile 0 (component 0, ko=0) into buf0
    stage_op<4>(A,  K, m0, 0, &lds[0],     srow, sl, tid);
    stage_op<2>(Wq, K, n0, 0, &lds[16384], srow, sl, tid);

    #pragma unroll 1
    for (int kt = 0; kt < NKT; ++kt) {
        if (kt == KT || kt == 2*KT) {     // component boundary: shift accumulated value
            #pragma unroll
            for (int i = 0; i < 8; ++i)
                #pragma unroll
                for (int j = 0; j < 4; ++j)
                    acc[i][j] *= 128;
        }
        asm volatile("s_waitcnt vmcnt(0)" ::: "memory");   // tile kt landed (issued 1 tile ago)
        blockbar();

        const int cb = (kt & 1) * 24576;
        // ---- issue sweeps for tile kt+1 into the other buffer
        if (kt + 1 < NKT) {
            const int t1 = kt + 1;
            const int pb = (t1 & 1) * 24576;
            const int ko = (t1 % KT) * 64;
            const int8_t* Wc = Wq + (size_t)(t1 / KT) * HID * K;
            stage_op<4>(A,  K, m0, ko, &lds[pb],         srow, sl, tid);
            stage_op<2>(Wc, K, n0, ko, &lds[pb + 16384], srow, sl, tid);
        }

        // ---- 12 ds_read_b128 + 32 MFMA; compiler inserts counted lgkm waits
        i32x4 af[8], bf[4];
        #pragma unroll
        for (int i = 0; i < 8; ++i)
            af[i] = *(const i32x4*)&lds[cb + (wm*128 + i*16 + fr)*64 + swq];
        #pragma unroll
        for (int j = 0; j < 4; ++j)
            bf[j] = *(const i32x4*)&lds[cb + 16384 + (wn*64 + j*16 + fr)*64 + swq];
        __builtin_amdgcn_s_setprio(1);
        #pragma unroll
        for (int i = 0; i < 8; ++i)
            #pragma unroll
            for (int j = 0; j < 4; ++j)
                acc[i][j] = __builtin_amdgcn_mfma_i32_16x16x64_i8(af[i], bf[j], acc[i][j], 0, 0, 0);
        __builtin_amdgcn_s_setprio(0);
    }

    // ---- epilogue: per-lane LIF over 4 acc regs (= 4 timesteps of one row)
    const float inv = invs[0];
    float bs[4];
    #pragma unroll
    for (int j = 0; j < 4; ++j)
        bs[j] = bias[n0 + wn*64 + j*16 + fr];
    const int rowq = lq * 4;
    #pragma unroll
    for (int i = 0; i < 8; ++i) {
        int rowLocal = m0 + wm*128 + i*16 + rowq;   // t=0 row; rows rowLocal..+3 = t 0..3
        int r = rowLocal >> 2;
        #pragma unroll
        for (int j = 0; j < 4; ++j) {
            int n = n0 + wn*64 + j*16 + fr;
            float v = 0.0f, ssum = 0.0f;
            #pragma unroll
            for (int t = 0; t < 4; ++t) {
                float xv = (float)acc[i][j][t] * inv + bs[j];
                v = v + (xv - v) * 0.5f;
                float s = (v >= 1.0f) ? 1.0f : 0.0f;
                if constexpr (FINAL) ssum += s;
                else spk_out[(size_t)(rowLocal + t) * HID + n] = (int8_t)s;
                v = v * (1.0f - s);
            }
            if constexpr (FINAL) out_mean[(size_t)r * HID + n] = ssum * 0.25f;
        }
    }
}

// ---------------- out2[b,d] = mean over L of out1[b,l,d]
__global__ void mean_over_L(const float* __restrict__ out1, float* __restrict__ out2) {
    int idx = blockIdx.x * blockDim.x + threadIdx.x; // B*HID
    if (idx >= Bb*HID) return;
    int b = idx / HID, d = idx % HID;
    const float* p = out1 + (size_t)b*Lx*HID + d;
    float s = 0.0f;
    for (int l = 0; l < Lx; ++l) s += p[(size_t)l*HID];
    out2[idx] = s * (1.0f / Lx);
}

extern "C" void kernel_launch(void* const* d_in, const int* in_sizes, int n_in,
                              void* d_out, int out_size, void* d_ws, size_t ws_size,
                              hipStream_t stream) {
    const float* x      = (const float*)d_in[0];
    const float* cw     = (const float*)d_in[1];
    const float* cb     = (const float*)d_in[2];
    const float* g      = (const float*)d_in[3];
    const float* be     = (const float*)d_in[4];
    const float* mu     = (const float*)d_in[5];
    const float* var    = (const float*)d_in[6];
    const float* enc_w  = (const float*)d_in[7];
    const float* enc_b  = (const float*)d_in[8];
    const float* cell_w = (const float*)d_in[9];
    const float* cell_b = (const float*)d_in[10];

    float* out1 = (float*)d_out;                    // [RR][HID]
    float* out2 = out1 + (size_t)RR * HID;          // [B][HID]

    // ---- ws layout (~87 MB total)
    int8_t* spk1 = (int8_t*)d_ws;                   // RR*4*Cc = 16 MB
    int8_t* spkA = spk1 + (size_t)RR*4*Cc;          // MR*HID  = 32 MB
    int8_t* spkB = spkA + (size_t)MR*HID;           // MR*HID  = 32 MB
    int8_t* qEnc = spkB + (size_t)MR*HID;           // 3*HID*Cc
    int8_t* qC0  = qEnc + (size_t)3*HID*Cc;         // 3*HID*HID
    int8_t* qC1  = qC0  + (size_t)3*HID*HID;        // 3*HID*HID
    float*  amax = (float*)(qC1 + (size_t)3*HID*HID);
    float*  invv = amax + 3;

    // ---- weight quantization (exact 21-bit fixed point, per-matrix pow2 scale)
    zero_f<<<1, 4, 0, stream>>>(amax, 3);
    absmax_k<<<512, 256, 0, stream>>>(enc_w,  HID*Cc,  amax + 0);
    absmax_k<<<512, 256, 0, stream>>>(cell_w, HID*HID, amax + 1);
    absmax_k<<<512, 256, 0, stream>>>(cell_w + (size_t)HID*HID, HID*HID, amax + 2);
    quant_k<<<(HID*Cc  + 255)/256, 256, 0, stream>>>(enc_w,  HID*Cc,  amax + 0, qEnc, invv + 0);
    quant_k<<<(HID*HID + 255)/256, 256, 0, stream>>>(cell_w, HID*HID, amax + 1, qC0,  invv + 1);
    quant_k<<<(HID*HID + 255)/256, 256, 0, stream>>>(cell_w + (size_t)HID*HID, HID*HID, amax + 2, qC1, invv + 2);

    // ---- conv + BN + LIF
    conv_bn_lif<<<(Bb*Lx*Cc + 255)/256, 256, 0, stream>>>(x, cw, cb, g, be, mu, var, spk1);

    // ---- chunked trunk (2 chunks of 8192 rows); 1024 blocks = 2/CU
    for (int c = 0; c < NCHUNK; ++c) {
        const int8_t* a1 = spk1 + (size_t)c * MR * Cc;
        gemm_lif<Cc,  false><<<1024, 256, 0, stream>>>(a1,   qEnc, invv + 0, enc_b,      spkA, nullptr);
        gemm_lif<HID, false><<<1024, 256, 0, stream>>>(spkA, qC0,  invv + 1, cell_b,     spkB, nullptr);
        gemm_lif<HID, true ><<<1024, 256, 0, stream>>>(spkB, qC1,  invv + 2, cell_b+HID, nullptr,
                                                       out1 + (size_t)c * CH * HID);
    }

    mean_over_L<<<(Bb*HID + 255)/256, 256, 0, stream>>>(out1, out2);
}